// Round 3
// baseline (22.731 us; speedup 1.0000x reference)
//
#include <hip/hip_runtime.h>

// HeuristicBimodalCSRPool: per CSR segment, argmax (first index on ties) of
// x_proj[:, 0], gather that x_mod row (64 f32), plus a "seen" flag.
// 16 lanes per group; 16 groups per 256-thread block.
// csr staged through LDS (17 loads/block vs 512); single-touch global data
// uses non-temporal hints to skip L2 allocate churn.

typedef float f32x4 __attribute__((ext_vector_type(4)));

__global__ void __launch_bounds__(256)
csr_pool_kernel(const float* __restrict__ x_mod,
                const float* __restrict__ x_proj,
                const int* __restrict__ csr_idx,
                float* __restrict__ out_pool,
                float* __restrict__ out_seen,
                int n_groups, int n_elem) {
    __shared__ int s_csr[17];
    const int tid = threadIdx.x;
    const int block_g0 = blockIdx.x * 16;

    if (tid < 17) {
        int idx = block_g0 + tid;
        if (idx > n_groups) idx = n_groups;   // csr_idx has n_groups+1 entries
        s_csr[tid] = csr_idx[idx];
    }
    __syncthreads();

    const int lane16 = tid & 15;
    const int sub = tid >> 4;
    const int g = block_g0 + sub;
    if (g >= n_groups) return;

    const int start = s_csr[sub];
    const int end   = s_csr[sub + 1];

    // Per-lane scan: keep max value, first index achieving it.
    float best = -__builtin_inff();
    int   bidx = n_elem;  // sentinel
    for (int e = start + lane16; e < end; e += 16) {
        float v = __builtin_nontemporal_load(&x_proj[(size_t)e * 8]); // FEAT=0, N_PROJ=8
        if (v > best) { best = v; bidx = e; } // per-lane indices ascend -> strict '>' keeps first
    }

    // Subgroup (16-lane) butterfly reduce: max value, min index on ties.
    #pragma unroll
    for (int off = 8; off >= 1; off >>= 1) {
        float ov = __shfl_xor(best, off);
        int   oi = __shfl_xor(bidx, off);
        if (ov > best || (ov == best && oi < bidx)) { best = ov; bidx = oi; }
    }

    const bool seen = end > start;
    if (lane16 == 0) __builtin_nontemporal_store(seen ? 1.0f : 0.0f, &out_seen[g]);

    // Gather winning row: 16 lanes x float4 = 256 B coalesced.
    f32x4 v = {0.f, 0.f, 0.f, 0.f};
    if (seen) {
        const f32x4* src = (const f32x4*)(x_mod) + (size_t)bidx * 16 + lane16;
        v = __builtin_nontemporal_load(src);
    }
    __builtin_nontemporal_store(v, (f32x4*)out_pool + (size_t)g * 16 + lane16);
}

extern "C" void kernel_launch(void* const* d_in, const int* in_sizes, int n_in,
                              void* d_out, int out_size, void* d_ws, size_t ws_size,
                              hipStream_t stream) {
    // setup_inputs order: x_main (unused), x_mod, x_proj, csr_idx
    const float* x_mod  = (const float*)d_in[1];
    const float* x_proj = (const float*)d_in[2];
    const int*   csr    = (const int*)d_in[3];

    const int n_groups = in_sizes[3] - 1;     // csr_idx has n_groups+1 entries
    const int n_elem   = in_sizes[1] / 64;    // x_mod is (E, 64)

    float* out_pool = (float*)d_out;
    float* out_seen = out_pool + (size_t)n_groups * 64;

    const int groups_per_block = 16;          // 16 lanes per group
    dim3 block(256);
    dim3 grid((n_groups + groups_per_block - 1) / groups_per_block);
    csr_pool_kernel<<<grid, block, 0, stream>>>(x_mod, x_proj, csr, out_pool,
                                                out_seen, n_groups, n_elem);
}